// Round 2
// baseline (285.038 us; speedup 1.0000x reference)
//
#include <hip/hip_runtime.h>
#include <hip/hip_bf16.h>

#define N_NODES 4096
#define LOG2E 1.44269504088896340736f

typedef __attribute__((ext_vector_type(8))) short bf16x8;
typedef __attribute__((ext_vector_type(4))) short bf16x4;
typedef __attribute__((ext_vector_type(4))) float f32x4;

static __device__ __forceinline__ ushort f2bf(float x) {
    union { float f; unsigned u; } v; v.f = x;
    unsigned u = v.u;
    return (ushort)((u + 0x7FFFu + ((u >> 16) & 1u)) >> 16);   // RNE
}

// ---------------- mask pack: adj [4096][4096] f32 -> bits [4096][128] u32 ----
__global__ __launch_bounds__(256) void k_pack_mask(const float* __restrict__ adj,
                                                   unsigned* __restrict__ maskw) {
    int idx = blockIdx.x * 256 + threadIdx.x;          // 4096*128 words
    int row = idx >> 7, w = idx & 127;
    const float4* ap = (const float4*)(adj + (size_t)row * N_NODES + w * 32);
    unsigned bits = 0;
#pragma unroll
    for (int q = 0; q < 8; ++q) {
        float4 v = ap[q];
        bits |= (v.x > 0.f ? 1u : 0u) << (q * 4 + 0);
        bits |= (v.y > 0.f ? 1u : 0u) << (q * 4 + 1);
        bits |= (v.z > 0.f ? 1u : 0u) << (q * 4 + 2);
        bits |= (v.w > 0.f ? 1u : 0u) << (q * 4 + 3);
    }
    maskw[idx] = bits;
}

// ---------------- W [h][K][64] f32 -> Wt hi/lo bf16 [h][64][K] (K-major) -----
__global__ void k_prep_w(const float* __restrict__ W, ushort* __restrict__ Wh,
                         ushort* __restrict__ Wl, int kshift, int total) {
    int idx = blockIdx.x * 256 + threadIdx.x;
    if (idx >= total) return;
    int K = 1 << kshift;
    int n = idx & 63;
    int k = (idx >> 6) & (K - 1);
    int h = idx >> (6 + kshift);
    float v = W[idx];
    ushort hi = f2bf(v);
    union { unsigned u; float f; } hv; hv.u = ((unsigned)hi) << 16;
    ushort lo = f2bf(v - hv.f);
    size_t dst = ((size_t)h * 64 + n) * K + k;
    Wh[dst] = hi; Wl[dst] = lo;
}

// ---------------- H = X @ W (3-term split bf16 MFMA)
// writes Ht n-major [head][64][4096] bf16  +  fused f1/f2 row-dots ------------
__global__ __launch_bounds__(256) void k_gemm_h(const float* __restrict__ X,
        const ushort* __restrict__ Wh, const ushort* __restrict__ Wl,
        const float* __restrict__ a,
        ushort* __restrict__ Ht, float* __restrict__ f1c, float* __restrict__ f2c,
        int K) {
    int head = blockIdx.y;
    int t = threadIdx.x, wave = t >> 6, lane = t & 63;
    int c = lane & 15, g = lane >> 4;
    int i0 = blockIdx.x * 64 + wave * 16;
    const float* xrow = X + (size_t)(i0 + c) * K;
    f32x4 acc[4] = {};
    for (int k0 = 0; k0 < K; k0 += 32) {
        const float4* xp = (const float4*)(xrow + k0 + g * 8);
        float4 xa = xp[0], xb = xp[1];
        float xs[8] = {xa.x, xa.y, xa.z, xa.w, xb.x, xb.y, xb.z, xb.w};
        union { ushort s[8]; bf16x8 v; } ah, al;
#pragma unroll
        for (int e = 0; e < 8; ++e) {
            ushort hb = f2bf(xs[e]);
            ah.s[e] = hb;
            union { unsigned u; float f; } hv; hv.u = ((unsigned)hb) << 16;
            al.s[e] = f2bf(xs[e] - hv.f);
        }
#pragma unroll
        for (int nt = 0; nt < 4; ++nt) {
            size_t boff = ((size_t)head * 64 + nt * 16 + c) * K + k0 + g * 8;
            bf16x8 bh = *(const bf16x8*)(Wh + boff);
            bf16x8 bl = *(const bf16x8*)(Wl + boff);
            acc[nt] = __builtin_amdgcn_mfma_f32_16x16x32_bf16(ah.v, bh, acc[nt], 0, 0, 0);
            acc[nt] = __builtin_amdgcn_mfma_f32_16x16x32_bf16(al.v, bh, acc[nt], 0, 0, 0);
            acc[nt] = __builtin_amdgcn_mfma_f32_16x16x32_bf16(ah.v, bl, acc[nt], 0, 0, 0);
        }
    }
    // --- Ht n-major store: Ht[(head*64 + n)*4096 + i], 4 rows packed per store
#pragma unroll
    for (int nt = 0; nt < 4; ++nt) {
        union { ushort s[4]; bf16x4 v; } pk;
#pragma unroll
        for (int r = 0; r < 4; ++r) pk.s[r] = f2bf(acc[nt][r]);
        *(bf16x4*)(Ht + ((size_t)head * 64 + nt * 16 + c) * N_NODES + i0 + g * 4) = pk.v;
    }
    // --- fused f1/f2: row i = i0 + g*4 + r; reduce over c (n within nt via fma)
    float a1v[4], a2v[4];
#pragma unroll
    for (int nt = 0; nt < 4; ++nt) {
        a1v[nt] = a[head * 128 + nt * 16 + c];
        a2v[nt] = a[head * 128 + 64 + nt * 16 + c];
    }
#pragma unroll
    for (int r = 0; r < 4; ++r) {
        float f1 = 0.f, f2 = 0.f;
#pragma unroll
        for (int nt = 0; nt < 4; ++nt) {
            f1 = __builtin_fmaf(acc[nt][r], a1v[nt], f1);
            f2 = __builtin_fmaf(acc[nt][r], a2v[nt], f2);
        }
#pragma unroll
        for (int o = 1; o < 16; o <<= 1) {
            f1 += __shfl_xor(f1, o);
            f2 += __shfl_xor(f2, o);
        }
        if (c == 0) {
            int i = i0 + g * 4 + r;
            f1c[head * N_NODES + i] = (f1 - 16.0f) * LOG2E;   // fold -M shift
            f2c[head * N_NODES + i] = f2 * LOG2E;
        }
    }
}

// ---------------- masked flash attention — LDS-free -------------------------
// wave owns 16 rows; B-fragments read directly from n-major Ht (L1-resident);
// fixed shift M=16 folded into f1c; truncated-bf16 P with z summed from the
// truncated values (bias cancels exactly in the softmax ratio).
__global__ __launch_bounds__(256) void k_attn(const ushort* __restrict__ Ht,
        const float* __restrict__ f1c, const float* __restrict__ f2c,
        const unsigned* __restrict__ maskw,
        float* __restrict__ accP, float* __restrict__ Zp, int JS) {
    int rb = blockIdx.x, js = blockIdx.y, head = blockIdx.z;
    int t = threadIdx.x, wave = t >> 6, lane = t & 63;
    int c = lane & 15, g = lane >> 4;
    int i0 = rb * 64 + wave * 16;
    int irow = i0 + c;
    int jcount = N_NODES / JS;
    int j0 = js * jcount;
    const float F1 = f1c[head * N_NODES + irow];
    const float* f2p = f2c + (size_t)head * N_NODES + j0 + g * 8;
    const unsigned* mrow = maskw + (size_t)irow * 128;
    const ushort* bp0 = Ht + ((size_t)head * 64 +  0 + c) * N_NODES + j0 + g * 8;
    const ushort* bp1 = bp0 + (size_t)16 * N_NODES;
    const ushort* bp2 = bp0 + (size_t)32 * N_NODES;
    const ushort* bp3 = bp0 + (size_t)48 * N_NODES;
    const float NC = -12.8f * LOG2E;            // leakyrelu neg branch const
    f32x4 acc[4] = {};
    float z = 0.f;

    for (int jt = j0; jt < j0 + jcount; jt += 32) {
        bf16x8 b0 = *(const bf16x8*)bp0;  bp0 += 32;
        bf16x8 b1 = *(const bf16x8*)bp1;  bp1 += 32;
        bf16x8 b2 = *(const bf16x8*)bp2;  bp2 += 32;
        bf16x8 b3 = *(const bf16x8*)bp3;  bp3 += 32;
        unsigned w = mrow[jt >> 5];
        unsigned bits = (w >> (g * 8)) & 0xFFu;
        float4 fa = ((const float4*)f2p)[0];
        float4 fb = ((const float4*)f2p)[1];
        f2p += 32;
        float f2v[8] = {fa.x, fa.y, fa.z, fa.w, fb.x, fb.y, fb.z, fb.w};
        unsigned pu[8];
#pragma unroll
        for (int e = 0; e < 8; ++e) {
            float u = F1 + f2v[e];
            float tn = __builtin_fmaf(0.2f, u, NC);
            float m = fmaxf(u, tn);
            float p = __builtin_amdgcn_exp2f(m);
            p = ((bits >> e) & 1u) ? p : 0.f;
            union { float f; unsigned u; } pv; pv.f = p;
            pu[e] = pv.u;
        }
        union { unsigned w[4]; bf16x8 v; } pa;
#pragma unroll
        for (int q = 0; q < 4; ++q) {
            unsigned hi1 = pu[2 * q + 1] & 0xFFFF0000u;
            unsigned hi0 = pu[2 * q] & 0xFFFF0000u;
            pa.w[q] = hi1 | (hi0 >> 16);
            union { unsigned u; float f; } z0, z1;
            z0.u = hi0; z1.u = hi1;
            z += z0.f + z1.f;                    // z from truncated p: bias cancels
        }
        acc[0] = __builtin_amdgcn_mfma_f32_16x16x32_bf16(pa.v, b0, acc[0], 0, 0, 0);
        acc[1] = __builtin_amdgcn_mfma_f32_16x16x32_bf16(pa.v, b1, acc[1], 0, 0, 0);
        acc[2] = __builtin_amdgcn_mfma_f32_16x16x32_bf16(pa.v, b2, acc[2], 0, 0, 0);
        acc[3] = __builtin_amdgcn_mfma_f32_16x16x32_bf16(pa.v, b3, acc[3], 0, 0, 0);
    }
    z += __shfl_xor(z, 16);
    z += __shfl_xor(z, 32);
    int slice = head * JS + js;
    if (g == 0) Zp[(size_t)slice * N_NODES + irow] = z;
    float* ap = accP + ((size_t)slice * N_NODES + i0) * 64;
#pragma unroll
    for (int nt = 0; nt < 4; ++nt)
#pragma unroll
        for (int r = 0; r < 4; ++r)
            ap[(g * 4 + r) * 64 + nt * 16 + c] = acc[nt][r];
}

// ---------------- combine partials -------------------------------------------
__global__ __launch_bounds__(256) void k_combine1(const float* __restrict__ accP,
        const float* __restrict__ Zp, float* __restrict__ x2, int JS) {
    int idx = blockIdx.x * 256 + threadIdx.x;    // 8*4096*64
    int n = idx & 63, i = (idx >> 6) & 4095, h = idx >> 18;
    float s = 0.f, z = 0.f;
    for (int j = 0; j < JS; ++j) {
        int sl = h * JS + j;
        s += accP[((size_t)sl * N_NODES + i) * 64 + n];
        z += Zp[(size_t)sl * N_NODES + i];
    }
    float v = s / z;
    v = v > 0.f ? v : (__builtin_amdgcn_exp2f(v * LOG2E) - 1.f);   // elu
    x2[(size_t)i * 512 + h * 64 + n] = v;
}

__global__ __launch_bounds__(256) void k_combine2(const float* __restrict__ accP,
        const float* __restrict__ Zp, float* __restrict__ out, int JS) {
    int idx = blockIdx.x * 256 + threadIdx.x;    // 4096*64
    int n = idx & 63, i = idx >> 6;
    float s = 0.f, z = 0.f;
    for (int j = 0; j < JS; ++j) {
        s += accP[((size_t)j * N_NODES + i) * 64 + n];
        z += Zp[(size_t)j * N_NODES + i];
    }
    out[idx] = s / z;
}

extern "C" void kernel_launch(void* const* d_in, const int* in_sizes, int n_in,
                              void* d_out, int out_size, void* d_ws, size_t ws_size,
                              hipStream_t stream) {
    const float* features = (const float*)d_in[0];
    const float* adj      = (const float*)d_in[1];
    const float* W_heads  = (const float*)d_in[2];
    const float* a_heads  = (const float*)d_in[3];
    const float* W_out    = (const float*)d_in[4];
    const float* a_out    = (const float*)d_in[5];
    float* out = (float*)d_out;

    // fixed buffers ≈ 15.4 MB; accP/Zp scale with slices = max(8*JS1, JS2)
    size_t fixed = (size_t)(2 + 4) * 1024 * 1024 + 600 * 1024 + 700 * 1024
                 + (size_t)8 * 1024 * 1024 + 64 * 1024;
    int JS1 = 2, JS2 = 8;
    {
        size_t need32 = fixed + (size_t)32 * (N_NODES * 64 * 4 + N_NODES * 4) + 65536;
        if (ws_size >= need32) { JS1 = 4; JS2 = 16; }   // 8 waves/SIMD TLP
    }
    int slices = (8 * JS1 > JS2) ? 8 * JS1 : JS2;

    char* ws = (char*)d_ws;
    size_t off = 0;
    auto alloc = [&](size_t bytes) -> void* {
        void* p = ws + off; off = (off + bytes + 255) & ~(size_t)255; return p;
    };
    unsigned* maskw = (unsigned*)alloc((size_t)N_NODES * 128 * 4);
    ushort* Ht1 = (ushort*)alloc((size_t)8 * 64 * N_NODES * 2);   // n-major
    ushort* Ht2 = (ushort*)alloc((size_t)64 * N_NODES * 2);
    float* f1c1 = (float*)alloc((size_t)8 * N_NODES * 4);
    float* f2c1 = (float*)alloc((size_t)8 * N_NODES * 4);
    float* f1c2 = (float*)alloc((size_t)N_NODES * 4);
    float* f2c2 = (float*)alloc((size_t)N_NODES * 4);
    ushort* Wh1 = (ushort*)alloc((size_t)8 * 64 * 256 * 2);
    ushort* Wl1 = (ushort*)alloc((size_t)8 * 64 * 256 * 2);
    ushort* Wh2 = (ushort*)alloc((size_t)64 * 512 * 2);
    ushort* Wl2 = (ushort*)alloc((size_t)64 * 512 * 2);
    float* x2   = (float*)alloc((size_t)N_NODES * 512 * 4);
    float* accP = (float*)alloc((size_t)slices * N_NODES * 64 * 4);
    float* Zp   = (float*)alloc((size_t)slices * N_NODES * 4);

    hipLaunchKernelGGL(k_pack_mask, dim3(N_NODES * 128 / 256), dim3(256), 0, stream, adj, maskw);
    hipLaunchKernelGGL(k_prep_w, dim3((8 * 256 * 64 + 255) / 256), dim3(256), 0, stream,
                       W_heads, Wh1, Wl1, 8, 8 * 256 * 64);
    hipLaunchKernelGGL(k_prep_w, dim3((512 * 64 + 255) / 256), dim3(256), 0, stream,
                       W_out, Wh2, Wl2, 9, 512 * 64);
    // layer 1
    hipLaunchKernelGGL(k_gemm_h, dim3(64, 8), dim3(256), 0, stream,
                       features, Wh1, Wl1, a_heads, Ht1, f1c1, f2c1, 256);
    hipLaunchKernelGGL(k_attn, dim3(64, JS1, 8), dim3(256), 0, stream,
                       Ht1, f1c1, f2c1, maskw, accP, Zp, JS1);
    hipLaunchKernelGGL(k_combine1, dim3(8 * N_NODES * 64 / 256), dim3(256), 0, stream,
                       accP, Zp, x2, JS1);
    // layer 2
    hipLaunchKernelGGL(k_gemm_h, dim3(64, 1), dim3(256), 0, stream,
                       x2, Wh2, Wl2, a_out, Ht2, f1c2, f2c2, 512);
    hipLaunchKernelGGL(k_attn, dim3(64, JS2, 1), dim3(256), 0, stream,
                       Ht2, f1c2, f2c2, maskw, accP, Zp, JS2);
    hipLaunchKernelGGL(k_combine2, dim3(N_NODES * 64 / 256), dim3(256), 0, stream,
                       accP, Zp, out, JS2);
}

// Round 3
// 204.291 us; speedup vs baseline: 1.3953x; 1.3953x over previous
//
#include <hip/hip_runtime.h>
#include <hip/hip_bf16.h>

#define N_NODES 4096
#define LOG2E 1.44269504088896340736f
#define JT 256                      // j-tile staged in LDS per block

typedef __attribute__((ext_vector_type(8))) short bf16x8;
typedef __attribute__((ext_vector_type(4))) short bf16x4;
typedef __attribute__((ext_vector_type(4))) float f32x4;

static __device__ __forceinline__ ushort f2bf(float x) {
    union { float f; unsigned u; } v; v.f = x;
    unsigned u = v.u;
    return (ushort)((u + 0x7FFFu + ((u >> 16) & 1u)) >> 16);   // RNE
}

// ---------------- mask pack: adj [4096][4096] f32 -> bits [4096][128] u32 ----
__global__ __launch_bounds__(256) void k_pack_mask(const float* __restrict__ adj,
                                                   unsigned* __restrict__ maskw) {
    int idx = blockIdx.x * 256 + threadIdx.x;          // 4096*128 words
    int row = idx >> 7, w = idx & 127;
    const float4* ap = (const float4*)(adj + (size_t)row * N_NODES + w * 32);
    unsigned bits = 0;
#pragma unroll
    for (int q = 0; q < 8; ++q) {
        float4 v = ap[q];
        bits |= (v.x > 0.f ? 1u : 0u) << (q * 4 + 0);
        bits |= (v.y > 0.f ? 1u : 0u) << (q * 4 + 1);
        bits |= (v.z > 0.f ? 1u : 0u) << (q * 4 + 2);
        bits |= (v.w > 0.f ? 1u : 0u) << (q * 4 + 3);
    }
    maskw[idx] = bits;
}

// ---------------- W [h][K][64] f32 -> Wt hi/lo bf16 [h][64][K] (K-major) -----
__global__ void k_prep_w(const float* __restrict__ W, ushort* __restrict__ Wh,
                         ushort* __restrict__ Wl, int kshift, int total) {
    int idx = blockIdx.x * 256 + threadIdx.x;
    if (idx >= total) return;
    int K = 1 << kshift;
    int n = idx & 63;
    int k = (idx >> 6) & (K - 1);
    int h = idx >> (6 + kshift);
    float v = W[idx];
    ushort hi = f2bf(v);
    union { unsigned u; float f; } hv; hv.u = ((unsigned)hi) << 16;
    ushort lo = f2bf(v - hv.f);
    size_t dst = ((size_t)h * 64 + n) * K + k;
    Wh[dst] = hi; Wl[dst] = lo;
}

// ---------------- H = X @ W (3-term split bf16 MFMA)
// writes Ht n-major [head][64][4096] bf16  +  fused f1/f2 row-dots ------------
__global__ __launch_bounds__(256) void k_gemm_h(const float* __restrict__ X,
        const ushort* __restrict__ Wh, const ushort* __restrict__ Wl,
        const float* __restrict__ a,
        ushort* __restrict__ Ht, float* __restrict__ f1c, float* __restrict__ f2c,
        int K) {
    int head = blockIdx.y;
    int t = threadIdx.x, wave = t >> 6, lane = t & 63;
    int c = lane & 15, g = lane >> 4;
    int i0 = blockIdx.x * 64 + wave * 16;
    const float* xrow = X + (size_t)(i0 + c) * K;
    f32x4 acc[4] = {};
    for (int k0 = 0; k0 < K; k0 += 32) {
        const float4* xp = (const float4*)(xrow + k0 + g * 8);
        float4 xa = xp[0], xb = xp[1];
        float xs[8] = {xa.x, xa.y, xa.z, xa.w, xb.x, xb.y, xb.z, xb.w};
        union { ushort s[8]; bf16x8 v; } ah, al;
#pragma unroll
        for (int e = 0; e < 8; ++e) {
            ushort hb = f2bf(xs[e]);
            ah.s[e] = hb;
            union { unsigned u; float f; } hv; hv.u = ((unsigned)hb) << 16;
            al.s[e] = f2bf(xs[e] - hv.f);
        }
#pragma unroll
        for (int nt = 0; nt < 4; ++nt) {
            size_t boff = ((size_t)head * 64 + nt * 16 + c) * K + k0 + g * 8;
            bf16x8 bh = *(const bf16x8*)(Wh + boff);
            bf16x8 bl = *(const bf16x8*)(Wl + boff);
            acc[nt] = __builtin_amdgcn_mfma_f32_16x16x32_bf16(ah.v, bh, acc[nt], 0, 0, 0);
            acc[nt] = __builtin_amdgcn_mfma_f32_16x16x32_bf16(al.v, bh, acc[nt], 0, 0, 0);
            acc[nt] = __builtin_amdgcn_mfma_f32_16x16x32_bf16(ah.v, bl, acc[nt], 0, 0, 0);
        }
    }
    // --- Ht n-major store: Ht[(head*64 + n)*4096 + i], 4 rows packed per store
#pragma unroll
    for (int nt = 0; nt < 4; ++nt) {
        union { ushort s[4]; bf16x4 v; } pk;
#pragma unroll
        for (int r = 0; r < 4; ++r) pk.s[r] = f2bf(acc[nt][r]);
        *(bf16x4*)(Ht + ((size_t)head * 64 + nt * 16 + c) * N_NODES + i0 + g * 4) = pk.v;
    }
    // --- fused f1/f2: row i = i0 + g*4 + r; reduce over c
    float a1v[4], a2v[4];
#pragma unroll
    for (int nt = 0; nt < 4; ++nt) {
        a1v[nt] = a[head * 128 + nt * 16 + c];
        a2v[nt] = a[head * 128 + 64 + nt * 16 + c];
    }
#pragma unroll
    for (int r = 0; r < 4; ++r) {
        float f1 = 0.f, f2 = 0.f;
#pragma unroll
        for (int nt = 0; nt < 4; ++nt) {
            f1 = __builtin_fmaf(acc[nt][r], a1v[nt], f1);
            f2 = __builtin_fmaf(acc[nt][r], a2v[nt], f2);
        }
#pragma unroll
        for (int o = 1; o < 16; o <<= 1) {
            f1 += __shfl_xor(f1, o);
            f2 += __shfl_xor(f2, o);
        }
        if (c == 0) {
            int i = i0 + g * 4 + r;
            f1c[head * N_NODES + i] = (f1 - 16.0f) * LOG2E;   // fold -M shift
            f2c[head * N_NODES + i] = f2 * LOG2E;
        }
    }
}

// ---------------- masked flash attention — LDS-staged, swizzled, pipelined ---
// Block = 4 waves; wave owns 16 i-rows. Per 256-j tile: stage Ht[64n][256j]
// bf16 into 32KB LDS (reg-staged, 8x gload16 + 8x ds_write_b128 per thread,
// XOR-swizzled chunk = logical ^ (n&7) on BOTH source index and read addr).
// Next tile's loads issue before compute (T14). Fixed shift M=16 in f1c.
__global__ __launch_bounds__(256) void k_attn(const ushort* __restrict__ Ht,
        const float* __restrict__ f1c, const float* __restrict__ f2c,
        const unsigned* __restrict__ maskw,
        float* __restrict__ accP, float* __restrict__ Zp, int JS) {
    int rb = blockIdx.x, js = blockIdx.y, head = blockIdx.z;
    int t = threadIdx.x, wave = t >> 6, lane = t & 63;
    int c = lane & 15, g = lane >> 4, c7 = c & 7;
    int i0 = rb * 64 + wave * 16;
    int irow = i0 + c;
    int jcount = N_NODES / JS;
    int j0 = js * jcount;
    int ntiles = jcount / JT;
    const float F1 = f1c[head * N_NODES + irow];
    const float* f2p = f2c + (size_t)head * N_NODES + j0 + g * 8;
    const unsigned* mrow = maskw + (size_t)irow * 128 + (j0 >> 5);
    const float NC = -12.8f * LOG2E;            // leakyrelu neg branch const
    f32x4 acc[4] = {};
    float z = 0.f;

    __shared__ ushort Hs[64 * JT];              // 32 KB, swizzled chunks

    // staging geometry: round s covers rows n = s*8 + tn, chunk slot tc
    int tn = t >> 5, tc = t & 31;
    int sjc = tc ^ tn;                          // source logical chunk (n&7==tn)
    const ushort* sp = Ht + ((size_t)head * 64 + tn) * N_NODES + j0 + sjc * 8;
    unsigned wb = (unsigned)(tn * JT + tc * 8) * 2;   // LDS byte for round 0

    int4 stg[8];
#pragma unroll
    for (int s = 0; s < 8; ++s)
        stg[s] = *(const int4*)(sp + (size_t)s * 8 * N_NODES);
    sp += JT;

    for (int tile = 0; tile < ntiles; ++tile) {
        __syncthreads();                        // prev tile's reads done
#pragma unroll
        for (int s = 0; s < 8; ++s)
            *(int4*)((char*)Hs + wb + s * 8 * JT * 2) = stg[s];
        __syncthreads();
        if (tile + 1 < ntiles) {
#pragma unroll
            for (int s = 0; s < 8; ++s)
                stg[s] = *(const int4*)(sp + (size_t)s * 8 * N_NODES);
            sp += JT;
        }
#pragma unroll
        for (int itr = 0; itr < JT / 32; ++itr) {
            // B-frags: row r = nt*16+c, logical chunk itr*4+g, phys ^= c7
            unsigned cb = (unsigned)(((itr * 4 + g) ^ c7) << 4);
            bf16x8 b0 = *(const bf16x8*)((const char*)Hs + (c      ) * JT * 2 + cb);
            bf16x8 b1 = *(const bf16x8*)((const char*)Hs + (c + 16) * JT * 2 + cb);
            bf16x8 b2 = *(const bf16x8*)((const char*)Hs + (c + 32) * JT * 2 + cb);
            bf16x8 b3 = *(const bf16x8*)((const char*)Hs + (c + 48) * JT * 2 + cb);
            unsigned w = *mrow++;
            unsigned bits = (w >> (g * 8)) & 0xFFu;
            float4 fa = ((const float4*)f2p)[0];
            float4 fb = ((const float4*)f2p)[1];
            f2p += 32;
            float f2v[8] = {fa.x, fa.y, fa.z, fa.w, fb.x, fb.y, fb.z, fb.w};
            unsigned pu[8];
#pragma unroll
            for (int e = 0; e < 8; ++e) {
                float u = F1 + f2v[e];
                float tnn = __builtin_fmaf(0.2f, u, NC);
                float m = fmaxf(u, tnn);
                float p = __builtin_amdgcn_exp2f(m);
                p = ((bits >> e) & 1u) ? p : 0.f;
                union { float f; unsigned u; } pv; pv.f = p;
                pu[e] = pv.u;
            }
            union { unsigned w[4]; bf16x8 v; } pa;
#pragma unroll
            for (int q = 0; q < 4; ++q) {
                unsigned hi1 = pu[2 * q + 1] & 0xFFFF0000u;
                unsigned hi0 = pu[2 * q] & 0xFFFF0000u;
                pa.w[q] = hi1 | (hi0 >> 16);
                union { unsigned u; float f; } z0, z1;
                z0.u = hi0; z1.u = hi1;
                z += z0.f + z1.f;                // z from truncated p: bias cancels
            }
            acc[0] = __builtin_amdgcn_mfma_f32_16x16x32_bf16(pa.v, b0, acc[0], 0, 0, 0);
            acc[1] = __builtin_amdgcn_mfma_f32_16x16x32_bf16(pa.v, b1, acc[1], 0, 0, 0);
            acc[2] = __builtin_amdgcn_mfma_f32_16x16x32_bf16(pa.v, b2, acc[2], 0, 0, 0);
            acc[3] = __builtin_amdgcn_mfma_f32_16x16x32_bf16(pa.v, b3, acc[3], 0, 0, 0);
        }
    }
    z += __shfl_xor(z, 16);
    z += __shfl_xor(z, 32);
    int slice = head * JS + js;
    if (g == 0) Zp[(size_t)slice * N_NODES + irow] = z;
    float* ap = accP + ((size_t)slice * N_NODES + i0) * 64;
#pragma unroll
    for (int nt = 0; nt < 4; ++nt)
#pragma unroll
        for (int r = 0; r < 4; ++r)
            ap[(g * 4 + r) * 64 + nt * 16 + c] = acc[nt][r];
}

// ---------------- combine partials -------------------------------------------
__global__ __launch_bounds__(256) void k_combine1(const float* __restrict__ accP,
        const float* __restrict__ Zp, float* __restrict__ x2, int JS) {
    int idx = blockIdx.x * 256 + threadIdx.x;    // 8*4096*64
    int n = idx & 63, i = (idx >> 6) & 4095, h = idx >> 18;
    float s = 0.f, z = 0.f;
    for (int j = 0; j < JS; ++j) {
        int sl = h * JS + j;
        s += accP[((size_t)sl * N_NODES + i) * 64 + n];
        z += Zp[(size_t)sl * N_NODES + i];
    }
    float v = s / z;
    v = v > 0.f ? v : (__builtin_amdgcn_exp2f(v * LOG2E) - 1.f);   // elu
    x2[(size_t)i * 512 + h * 64 + n] = v;
}

__global__ __launch_bounds__(256) void k_combine2(const float* __restrict__ accP,
        const float* __restrict__ Zp, float* __restrict__ out, int JS) {
    int idx = blockIdx.x * 256 + threadIdx.x;    // 4096*64
    int n = idx & 63, i = idx >> 6;
    float s = 0.f, z = 0.f;
    for (int j = 0; j < JS; ++j) {
        s += accP[((size_t)j * N_NODES + i) * 64 + n];
        z += Zp[(size_t)j * N_NODES + i];
    }
    out[idx] = s / z;
}

extern "C" void kernel_launch(void* const* d_in, const int* in_sizes, int n_in,
                              void* d_out, int out_size, void* d_ws, size_t ws_size,
                              hipStream_t stream) {
    const float* features = (const float*)d_in[0];
    const float* adj      = (const float*)d_in[1];
    const float* W_heads  = (const float*)d_in[2];
    const float* a_heads  = (const float*)d_in[3];
    const float* W_out    = (const float*)d_in[4];
    const float* a_out    = (const float*)d_in[5];
    float* out = (float*)d_out;

    // fixed (non-slice) buffers ≈ 16.2 MB; per-slice accP+Zp ≈ 1.07 MB
    size_t fixed = 16200000;
    size_t per_slice = (size_t)N_NODES * 64 * 4 + N_NODES * 4 + 512;
    int JS1 = 2, JS2 = 16;                       // 1024 blocks each (4/CU)
    if (ws_size < fixed + 16 * per_slice + 65536) { JS1 = 1; JS2 = 8; }
    int slices = (8 * JS1 > JS2) ? 8 * JS1 : JS2;

    char* ws = (char*)d_ws;
    size_t off = 0;
    auto alloc = [&](size_t bytes) -> void* {
        void* p = ws + off; off = (off + bytes + 255) & ~(size_t)255; return p;
    };
    unsigned* maskw = (unsigned*)alloc((size_t)N_NODES * 128 * 4);
    ushort* Ht1 = (ushort*)alloc((size_t)8 * 64 * N_NODES * 2);   // n-major
    ushort* Ht2 = (ushort*)alloc((size_t)64 * N_NODES * 2);
    float* f1c1 = (float*)alloc((size_t)8 * N_NODES * 4);
    float* f2c1 = (float*)alloc((size_t)8 * N_NODES * 4);
    float* f1c2 = (float*)alloc((size_t)N_NODES * 4);
    float* f2c2 = (float*)alloc((size_t)N_NODES * 4);
    ushort* Wh1 = (ushort*)alloc((size_t)8 * 64 * 256 * 2);
    ushort* Wl1 = (ushort*)alloc((size_t)8 * 64 * 256 * 2);
    ushort* Wh2 = (ushort*)alloc((size_t)64 * 512 * 2);
    ushort* Wl2 = (ushort*)alloc((size_t)64 * 512 * 2);
    float* x2   = (float*)alloc((size_t)N_NODES * 512 * 4);
    float* accP = (float*)alloc((size_t)slices * N_NODES * 64 * 4);
    float* Zp   = (float*)alloc((size_t)slices * N_NODES * 4);

    hipLaunchKernelGGL(k_pack_mask, dim3(N_NODES * 128 / 256), dim3(256), 0, stream, adj, maskw);
    hipLaunchKernelGGL(k_prep_w, dim3((8 * 256 * 64 + 255) / 256), dim3(256), 0, stream,
                       W_heads, Wh1, Wl1, 8, 8 * 256 * 64);
    hipLaunchKernelGGL(k_prep_w, dim3((512 * 64 + 255) / 256), dim3(256), 0, stream,
                       W_out, Wh2, Wl2, 9, 512 * 64);
    // layer 1
    hipLaunchKernelGGL(k_gemm_h, dim3(64, 8), dim3(256), 0, stream,
                       features, Wh1, Wl1, a_heads, Ht1, f1c1, f2c1, 256);
    hipLaunchKernelGGL(k_attn, dim3(64, JS1, 8), dim3(256), 0, stream,
                       Ht1, f1c1, f2c1, maskw, accP, Zp, JS1);
    hipLaunchKernelGGL(k_combine1, dim3(8 * N_NODES * 64 / 256), dim3(256), 0, stream,
                       accP, Zp, x2, JS1);
    // layer 2
    hipLaunchKernelGGL(k_gemm_h, dim3(64, 1), dim3(256), 0, stream,
                       x2, Wh2, Wl2, a_out, Ht2, f1c2, f2c2, 512);
    hipLaunchKernelGGL(k_attn, dim3(64, JS2, 1), dim3(256), 0, stream,
                       Ht2, f1c2, f2c2, maskw, accP, Zp, JS2);
    hipLaunchKernelGGL(k_combine2, dim3(N_NODES * 64 / 256), dim3(256), 0, stream,
                       accP, Zp, out, JS2);
}